// Round 7
// baseline (584.919 us; speedup 1.0000x reference)
//
#include <hip/hip_runtime.h>

#define N_NODES 50000
#define N_PAD   50176   // 392*128, covers GEMM tile over-read
#define N_EDGES 800000
#define DIM     256
#define KDIM    512     // concat [agg | x]
#define BN_EPS  1e-5f
#define SCAN_NB ((N_NODES + 1023) / 1024)   // 49

typedef __attribute__((ext_vector_type(8))) short short8;
typedef __attribute__((ext_vector_type(4))) float floatx4;

__device__ __forceinline__ float bf2f(unsigned short u) {
    return __uint_as_float(((unsigned int)u) << 16);
}
__device__ __forceinline__ unsigned short f2bf(float f) {
    unsigned int b = __float_as_uint(f);
    b = (b + 0x7FFF + ((b >> 16) & 1)) >> 16;   // RNE
    return (unsigned short)b;
}

__device__ __forceinline__ void gload_lds16(const void* g, void* l) {
    __builtin_amdgcn_global_load_lds(
        (const __attribute__((address_space(1))) unsigned int*)g,
        (__attribute__((address_space(3))) unsigned int*)l, 16, 0, 0);
}

// ---------------- CSR build (once per launch) -------------------------------

__global__ void k_deg_count(const int* __restrict__ dst, int* __restrict__ degi) {
    int e = blockIdx.x * blockDim.x + threadIdx.x;
    if (e < N_EDGES) atomicAdd(&degi[dst[e]], 1);
}

// Hierarchical scan: per-block inclusive scan + block sums.
__global__ void k_scan1(const int* __restrict__ degi, int* __restrict__ off,
                        float* __restrict__ inv_deg, int* __restrict__ bsums) {
    __shared__ int buf[1024];
    int i = blockIdx.x * 1024 + threadIdx.x;
    int v = (i < N_NODES) ? degi[i] : 0;
    if (i < N_NODES) inv_deg[i] = 1.0f / (float)max(v, 1);
    buf[threadIdx.x] = v;
    __syncthreads();
    for (int s = 1; s < 1024; s <<= 1) {
        int t = (threadIdx.x >= s) ? buf[threadIdx.x - s] : 0;
        __syncthreads();
        buf[threadIdx.x] += t;
        __syncthreads();
    }
    if (i < N_NODES) off[i + 1] = buf[threadIdx.x];   // local inclusive
    if (threadIdx.x == 1023) bsums[blockIdx.x] = buf[1023];
    if (i == 0) off[0] = 0;
}

// One wave scans the 49 block sums -> exclusive offsets, in place.
__global__ void k_scan2(int* __restrict__ bsums) {
    int t = threadIdx.x;   // 64 threads
    int orig = (t < SCAN_NB) ? bsums[t] : 0;
    int v = orig;
    for (int s = 1; s < 64; s <<= 1) {
        int u = __shfl_up(v, s, 64);
        if (t >= s) v += u;
    }
    if (t < SCAN_NB) bsums[t] = v - orig;   // exclusive
}

__global__ void k_scan3(int* __restrict__ off, const int* __restrict__ bsums) {
    int i = blockIdx.x * 1024 + threadIdx.x;
    if (i < N_NODES) off[i + 1] += bsums[blockIdx.x];
}

__global__ void k_fill(const int* __restrict__ src, const int* __restrict__ dst,
                       const int* __restrict__ off, int* __restrict__ cursor,
                       int* __restrict__ csr_src) {
    int e = blockIdx.x * blockDim.x + threadIdx.x;
    if (e < N_EDGES) {
        int d = dst[e];
        int pos = atomicAdd(&cursor[d], 1);
        csr_src[off[d] + pos] = src[e];
    }
}

// ---------------- weight prep: Wcat_t[l][n][k] bf16 (transposed concat) -----

__global__ void k_prep_w(const float* __restrict__ Wl, const float* __restrict__ Wr,
                         unsigned short* __restrict__ Wcat) {
    int gid = blockIdx.x * blockDim.x + threadIdx.x;   // 3*256*512
    if (gid >= 3 * DIM * KDIM) return;
    int k = gid & (KDIM - 1);
    int n = (gid >> 9) & (DIM - 1);
    int l = gid >> 17;
    float v = (k < DIM) ? Wl[(size_t)l * DIM * DIM + (size_t)k * DIM + n]
                        : Wr[(size_t)l * DIM * DIM + (size_t)(k - DIM) * DIM + n];
    Wcat[gid] = f2bf(v);
}

// ---------------- x0 -> bf16 into Acat cols 256..511 ------------------------

__global__ void k_x2bf(const float* __restrict__ x, unsigned short* __restrict__ Acat) {
    size_t i = (size_t)blockIdx.x * blockDim.x + threadIdx.x;  // float4 units
    if (i >= (size_t)N_NODES * (DIM / 4)) return;
    int node = (int)(i >> 6);
    int c = ((int)i & 63) * 4;
    float4 v = ((const float4*)x)[i];
    ushort4 o; o.x = f2bf(v.x); o.y = f2bf(v.y); o.z = f2bf(v.z); o.w = f2bf(v.w);
    *(ushort4*)&Acat[(size_t)node * KDIM + DIM + c] = o;
}

// ---------------- mean aggregation: one node per HALF-wave, 16B/lane, x8 MLP

__device__ __forceinline__ void addv(float* a, uint4 v) {
    unsigned int w[4] = {v.x, v.y, v.z, v.w};
    #pragma unroll
    for (int q = 0; q < 4; ++q) {
        a[2 * q + 0] += bf2f((unsigned short)(w[q] & 0xFFFF));
        a[2 * q + 1] += bf2f((unsigned short)(w[q] >> 16));
    }
}

__global__ __launch_bounds__(256) void k_aggregate(
        const unsigned short* __restrict__ Acat_x,
        const int* __restrict__ off,
        const int* __restrict__ csr_src,
        const float* __restrict__ inv_deg,
        unsigned short* __restrict__ Acat_agg) {
    int gid = blockIdx.x * blockDim.x + threadIdx.x;
    int node = gid >> 5;               // one node per 32-lane group
    int lane = threadIdx.x & 31;       // 8 bf16 (16 B) per lane
    if (node >= N_NODES) return;
    int beg = off[node], end = off[node + 1];
    float a[8];
    #pragma unroll
    for (int q = 0; q < 8; ++q) a[q] = 0.f;
    const unsigned short* xb = Acat_x + DIM + lane * 8;   // x half of Acat row

    int e = beg;
    for (; e + 8 <= end; e += 8) {
        uint4 v0 = *(const uint4*)(xb + (size_t)csr_src[e + 0] * KDIM);
        uint4 v1 = *(const uint4*)(xb + (size_t)csr_src[e + 1] * KDIM);
        uint4 v2 = *(const uint4*)(xb + (size_t)csr_src[e + 2] * KDIM);
        uint4 v3 = *(const uint4*)(xb + (size_t)csr_src[e + 3] * KDIM);
        uint4 v4 = *(const uint4*)(xb + (size_t)csr_src[e + 4] * KDIM);
        uint4 v5 = *(const uint4*)(xb + (size_t)csr_src[e + 5] * KDIM);
        uint4 v6 = *(const uint4*)(xb + (size_t)csr_src[e + 6] * KDIM);
        uint4 v7 = *(const uint4*)(xb + (size_t)csr_src[e + 7] * KDIM);
        addv(a, v0); addv(a, v1); addv(a, v2); addv(a, v3);
        addv(a, v4); addv(a, v5); addv(a, v6); addv(a, v7);
    }
    for (; e + 4 <= end; e += 4) {
        uint4 v0 = *(const uint4*)(xb + (size_t)csr_src[e + 0] * KDIM);
        uint4 v1 = *(const uint4*)(xb + (size_t)csr_src[e + 1] * KDIM);
        uint4 v2 = *(const uint4*)(xb + (size_t)csr_src[e + 2] * KDIM);
        uint4 v3 = *(const uint4*)(xb + (size_t)csr_src[e + 3] * KDIM);
        addv(a, v0); addv(a, v1); addv(a, v2); addv(a, v3);
    }
    for (; e < end; ++e) {
        uint4 v = *(const uint4*)(xb + (size_t)csr_src[e] * KDIM);
        addv(a, v);
    }

    float inv = inv_deg[node];
    unsigned int w[4];
    #pragma unroll
    for (int q = 0; q < 4; ++q)
        w[q] = (unsigned int)f2bf(a[2 * q] * inv) |
               ((unsigned int)f2bf(a[2 * q + 1] * inv) << 16);
    uint4 o; o.x = w[0]; o.y = w[1]; o.z = w[2]; o.w = w[3];
    *(uint4*)&Acat_agg[(size_t)node * KDIM + lane * 8] = o;
}

// ---------------- bf16 MFMA GEMM: H(bf16) = Acat @ Wcat_t^T + bias ----------
// 2-phase double-buffered pipeline: STAGE(next) issued BEFORE compute(cur);
// single __syncthreads per K-step drains the (now latency-covered) loads.
// Fused BN-stats: per-column sum/sumsq via shfl-reduce + atomics.

__global__ __launch_bounds__(256) void k_gemm_mfma(
        const unsigned short* __restrict__ A,
        const unsigned short* __restrict__ Bt,
        const float* __restrict__ bias, unsigned short* __restrict__ H,
        float* __restrict__ ssum, float* __restrict__ ssq) {
    __shared__ __align__(16) short Alds[2][128 * 32];   // 2 x 8 KB
    __shared__ __align__(16) short Blds[2][128 * 32];   // 2 x 8 KB
    int tid = threadIdx.x;
    int wid = tid >> 6;
    int lane = tid & 63;
    int wm = wid >> 1, wn = wid & 1;
    int brow = blockIdx.x * 128;
    int bcol = blockIdx.y * 128;

    floatx4 acc[4][4];
    #pragma unroll
    for (int i = 0; i < 4; ++i)
        #pragma unroll
        for (int j = 0; j < 4; ++j) acc[i][j] = (floatx4){0.f, 0.f, 0.f, 0.f};

    int st_r0 = (lane >> 2);          // row within 16-row chunk
    int st_s  = lane & 3;             // stored 16B slot
    int rb = lane & 15;               // frag row/col within 16
    int k16r = lane >> 4;             // frag k-slot (8 bf16)

    auto stage = [&](int buf, int kt) {
        int k0 = kt * 32;
        #pragma unroll
        for (int q = 0; q < 2; ++q) {
            int c = wid * 2 + q;
            int r = c * 16 + st_r0;
            int k16 = (st_s - (r >> 1)) & 3;   // inverse swizzle on global source
            gload_lds16(A + (size_t)(brow + r) * KDIM + k0 + k16 * 8, &Alds[buf][c * 512]);
            gload_lds16(Bt + (size_t)(bcol + r) * KDIM + k0 + k16 * 8, &Blds[buf][c * 512]);
        }
    };

    stage(0, 0);
    __syncthreads();
    int cur = 0;
    for (int kt = 0; kt < KDIM / 32; ++kt) {
        if (kt + 1 < KDIM / 32) stage(cur ^ 1, kt + 1);   // prefetch next tile

        short8 af[4], bfr[4];
        #pragma unroll
        for (int i = 0; i < 4; ++i) {
            int ra = wm * 64 + i * 16 + rb;
            int sa = (k16r + (ra >> 1)) & 3;
            af[i] = *(const short8*)&Alds[cur][ra * 32 + sa * 8];
            int rc = wn * 64 + i * 16 + rb;
            int sc = (k16r + (rc >> 1)) & 3;
            bfr[i] = *(const short8*)&Blds[cur][rc * 32 + sc * 8];
        }
        #pragma unroll
        for (int i = 0; i < 4; ++i)
            #pragma unroll
            for (int j = 0; j < 4; ++j)
                acc[i][j] = __builtin_amdgcn_mfma_f32_16x16x32_bf16(
                    af[i], bfr[j], acc[i][j], 0, 0, 0);
        __syncthreads();   // drains prefetch (latency covered by compute above)
        cur ^= 1;
    }

    int rg = lane >> 4;
    #pragma unroll
    for (int j = 0; j < 4; ++j) {
        int col = bcol + wn * 64 + j * 16 + rb;
        float bv = bias[col];
        float s = 0.f, s2 = 0.f;
        #pragma unroll
        for (int i = 0; i < 4; ++i) {
            #pragma unroll
            for (int q = 0; q < 4; ++q) {
                int row = brow + wm * 64 + i * 16 + rg * 4 + q;
                float o = acc[i][j][q] + bv;
                unsigned short hb = f2bf(o);
                if (row < N_NODES) {
                    H[(size_t)row * DIM + col] = hb;
                    float of = bf2f(hb);
                    s += of;
                    s2 = fmaf(of, of, s2);
                }
            }
        }
        s  += __shfl_xor(s, 16);
        s  += __shfl_xor(s, 32);
        s2 += __shfl_xor(s2, 16);
        s2 += __shfl_xor(s2, 32);
        if (rg == 0) {
            atomicAdd(&ssum[col], s);
            atomicAdd(&ssq[col], s2);
        }
    }
}

// ---------------- normalize (+fused BN finalize per block) ------------------
// last=0: write bf16 x into Acat cols 256..511. last=1: fp32 to outF.

__global__ void k_norm_relu(const unsigned short* __restrict__ H,
                            const float* __restrict__ ssum,
                            const float* __restrict__ ssq,
                            const float* __restrict__ gamma,
                            const float* __restrict__ beta,
                            float* __restrict__ outF,
                            unsigned short* __restrict__ Acat, int last) {
    __shared__ float sc[DIM], sh[DIM];
    {
        int c = threadIdx.x;
        float mu  = ssum[c] * (1.0f / N_NODES);
        float var = ssq[c] * (1.0f / N_NODES) - mu * mu;
        float rstd = rsqrtf(var + BN_EPS);
        float s = rstd * gamma[c];
        sc[c] = s;
        sh[c] = beta[c] - mu * s;
    }
    __syncthreads();
    size_t total8 = (size_t)N_NODES * DIM / 8;   // uint4 = 8 bf16
    for (size_t i = (size_t)blockIdx.x * blockDim.x + threadIdx.x; i < total8;
         i += (size_t)gridDim.x * blockDim.x) {
        uint4 raw = ((const uint4*)H)[i];
        int node = (int)(i >> 5);            // DIM/8 = 32 vectors per row
        int c = ((int)i & 31) * 8;
        unsigned int w[4] = {raw.x, raw.y, raw.z, raw.w};
        float o[8];
        #pragma unroll
        for (int q = 0; q < 4; ++q) {
            float lo = bf2f((unsigned short)(w[q] & 0xFFFF));
            float hi = bf2f((unsigned short)(w[q] >> 16));
            o[q * 2 + 0] = fmaxf(fmaf(lo, sc[c + q * 2 + 0], sh[c + q * 2 + 0]), 0.f);
            o[q * 2 + 1] = fmaxf(fmaf(hi, sc[c + q * 2 + 1], sh[c + q * 2 + 1]), 0.f);
        }
        if (last) {
            float4 f0 = make_float4(o[0], o[1], o[2], o[3]);
            float4 f1 = make_float4(o[4], o[5], o[6], o[7]);
            *(float4*)(outF + (size_t)node * DIM + c)     = f0;
            *(float4*)(outF + (size_t)node * DIM + c + 4) = f1;
        } else {
            uint4 u;
            unsigned int uw[4];
            #pragma unroll
            for (int q = 0; q < 4; ++q)
                uw[q] = (unsigned int)f2bf(o[q * 2 + 0]) |
                        ((unsigned int)f2bf(o[q * 2 + 1]) << 16);
            u.x = uw[0]; u.y = uw[1]; u.z = uw[2]; u.w = uw[3];
            *(uint4*)&Acat[(size_t)node * KDIM + DIM + c] = u;
        }
    }
}

// ---------------- launch ----------------------------------------------------

extern "C" void kernel_launch(void* const* d_in, const int* in_sizes, int n_in,
                              void* d_out, int out_size, void* d_ws, size_t ws_size,
                              hipStream_t stream) {
    const float* x0    = (const float*)d_in[0];
    const float* Wl    = (const float*)d_in[1];
    const float* bl    = (const float*)d_in[2];
    const float* Wr    = (const float*)d_in[3];
    const float* gamma = (const float*)d_in[4];
    const float* beta  = (const float*)d_in[5];
    const int*   ei    = (const int*)d_in[6];
    const int* e_src = ei;
    const int* e_dst = ei + N_EDGES;

    char* ws = (char*)d_ws;
    size_t off = 0;
    auto alloc = [&](size_t bytes) { char* p = ws + off; off = (off + bytes + 255) & ~(size_t)255; return p; };
    unsigned short* Acat = (unsigned short*)alloc((size_t)N_PAD * KDIM * 2);  // 51.4 MB
    unsigned short* Hbuf = (unsigned short*)alloc((size_t)N_PAD * DIM * 2);   // 25.7 MB
    unsigned short* Wcat = (unsigned short*)alloc((size_t)3 * DIM * KDIM * 2);
    int*   csr_src = (int*)alloc((size_t)N_EDGES * 4);
    int*   csr_off = (int*)alloc((size_t)(N_NODES + 1) * 4);
    int*   degi    = (int*)alloc((size_t)N_NODES * 4);
    int*   cursor  = (int*)alloc((size_t)N_NODES * 4);
    int*   bsums   = (int*)alloc((size_t)SCAN_NB * 4);
    float* inv_deg = (float*)alloc((size_t)N_NODES * 4);
    float* stats   = (float*)alloc((size_t)3 * 2 * DIM * 4);   // [layer][ssum|ssq][DIM]
    (void)ws_size;

    hipMemsetAsync(degi, 0, (size_t)N_NODES * 4, stream);
    hipMemsetAsync(cursor, 0, (size_t)N_NODES * 4, stream);
    hipMemsetAsync(stats, 0, (size_t)3 * 2 * DIM * 4, stream);

    int eb = (N_EDGES + 255) / 256;
    k_deg_count<<<eb, 256, 0, stream>>>(e_dst, degi);
    k_scan1<<<SCAN_NB, 1024, 0, stream>>>(degi, csr_off, inv_deg, bsums);
    k_scan2<<<1, 64, 0, stream>>>(bsums);
    k_scan3<<<SCAN_NB, 1024, 0, stream>>>(csr_off, bsums);
    k_fill<<<eb, 256, 0, stream>>>(e_src, e_dst, csr_off, cursor, csr_src);
    k_prep_w<<<(3 * DIM * KDIM + 255) / 256, 256, 0, stream>>>(Wl, Wr, Wcat);
    k_x2bf<<<(N_NODES * (DIM / 4) + 255) / 256, 256, 0, stream>>>(x0, Acat);

    for (int l = 0; l < 3; ++l) {
        float* ssum_l = stats + (size_t)l * 2 * DIM;
        float* ssq_l  = ssum_l + DIM;
        k_aggregate<<<(N_NODES * 32 + 255) / 256, 256, 0, stream>>>(
            Acat, csr_off, csr_src, inv_deg, Acat);
        k_gemm_mfma<<<dim3((N_NODES + 127) / 128, DIM / 128), 256, 0, stream>>>(
            Acat, Wcat + (size_t)l * DIM * KDIM, bl + (size_t)l * DIM, Hbuf, ssum_l, ssq_l);
        k_norm_relu<<<2048, 256, 0, stream>>>(Hbuf, ssum_l, ssq_l,
                                              gamma + (size_t)l * DIM, beta + (size_t)l * DIM,
                                              (float*)d_out, Acat, (l == 2) ? 1 : 0);
    }
}